// Round 18
// baseline (113.419 us; speedup 1.0000x reference)
//
#include <hip/hip_runtime.h>
#include <hip/hip_cooperative_groups.h>
#include <math.h>

#pragma clang fp contract(off)

namespace cg = cooperative_groups;

#define NB 4
#define NN 8000
#define NC 91
#define CM1 90
#define CAP 2048          // outer kept bound (proven sufficient rounds 1-17)
#define ACAP 256          // chunk-A padded size
#define ATHR 192          // chunk-A histogram bound
#define GCAP 65536
#define RPB 32            // rows per block in cand_kernel
#define BPI (NN / RPB)    // 250 blocks per image
#define LCAP 608          // = RPB*19 (hard bound: <=19 scores>0.05 per row)
#define GWB 16            // wide blocks per image for hist/gather
#define MWB 4             // matrix sub-blocks per image (64 rows each)

// ws layout (32-bit words). Hot counters padded (round-10 lesson).
#define CNT_W(b) ((b) * 64)
#define MAX_W(b) (256 + (b) * 64)
#define CNTA_W(b) (512 + (b) * 64)
#define CNTR_W(b) (768 + (b) * 64)
#define HIST_OFF 1024                // NB*1024 global hist
#define ZERO_WORDS (HIST_OFF + NB * 1024)   // 5120
#define GBOX_OFF 5120                        // NB*GCAP float4
#define GSC_OFF (GBOX_OFF + NB * GCAP * 4)
#define GOID_OFF (GSC_OFF + NB * GCAP)
#define ABOX_OFF (GOID_OFF + NB * GCAP)      // NB*ACAP float4
#define AKEY_OFF (ABOX_OFF + NB * ACAP * 4)  // NB*ACAP u64
#define RBOX_OFF (AKEY_OFF + NB * ACAP * 2)  // NB*CAP float4
#define RKEY_OFF (RBOX_OFF + NB * CAP * 4)   // NB*CAP u64
#define MTX_OFF (RKEY_OFF + NB * CAP * 2)    // NB*1024 u64 suppression matrix
#define SKEY_OFF (MTX_OFF + NB * 2048)       // NB*256 u64 sorted keys
#define SBOX_OFF (SKEY_OFF + NB * 512)       // NB*256 float4 sorted boxes
#define SLBL_OFF (SBOX_OFF + NB * 1024)      // NB*256 int sorted labels

// cand (round-15/16/17-proven): 16 lanes/row, in-register softmax tree +
// 4 shfl_xor, wave-aggregated ballot compaction, padded global counters.
__global__ void __launch_bounds__(256) cand_kernel(const float* __restrict__ logits,
                                                   const float* __restrict__ rel,
                                                   const float* __restrict__ props,
                                                   int* __restrict__ ws_i,
                                                   float* __restrict__ ws_f) {
  const int blk = blockIdx.x;
  const int b = blk / BPI;
  const int ib = blk - b * BPI;
  const int t = threadIdx.x;
  const int L = t & 15;
  const int grp = t >> 4;
  const int lane = t & 63;

  __shared__ float sbx[LCAP][4];
  __shared__ float ssb[LCAP];
  __shared__ int soidb[LCAP];
  __shared__ int scnt;
  __shared__ int smaxs;
  __shared__ int sgbase;
  if (t == 0) { scnt = 0; smaxs = 0; }
  __syncthreads();

  int tmax = 0;

  for (int i = 0; i < RPB / 16; ++i) {
    const int row = b * NN + ib * RPB + i * 16 + grp;
    const float* lp = logits + (size_t)row * NC;

    float lv[6];
#pragma unroll
    for (int j = 0; j < 6; ++j) {
      const int k = L + 16 * j;
      lv[j] = (k < NC) ? lp[k] : -INFINITY;
    }
    float tm0 = fmax(lv[0], lv[4]), tm1 = fmax(lv[1], lv[5]);
    float tm2 = lv[2], tm3 = lv[3];
    float um0 = fmax(tm0, tm2), um1 = fmax(tm1, tm3);
    float m = fmax(um0, um1);
    m = fmaxf(m, __shfl_xor(m, 8));
    m = fmaxf(m, __shfl_xor(m, 4));
    m = fmaxf(m, __shfl_xor(m, 2));
    m = fmaxf(m, __shfl_xor(m, 1));

    float ev[6];
#pragma unroll
    for (int j = 0; j < 6; ++j) {
      const int k = L + 16 * j;
      ev[j] = (k < NC) ? expf(lv[j] - m) : 0.0f;
    }
    float ts0 = ev[0] + ev[4], ts1 = ev[1] + ev[5];
    float ts2 = ev[2], ts3 = ev[3];
    float us0 = ts0 + ts2, us1 = ts1 + ts3;
    float sum = us0 + us1;
    sum += __shfl_xor(sum, 8);
    sum += __shfl_xor(sum, 4);
    sum += __shfl_xor(sum, 2);
    sum += __shfl_xor(sum, 1);

    const float4 p = reinterpret_cast<const float4*>(props)[row];
    const float w = p.z - p.x, h = p.w - p.y;
    const float cx = p.x + 0.5f * w, cy = p.y + 0.5f * h;

#pragma unroll
    for (int j = 0; j < 6; ++j) {
      const int c = L + 16 * j;
      bool valid = false;
      float x1 = 0.f, y1 = 0.f, x2 = 0.f, y2 = 0.f, score = 0.f;
      if (c >= 1 && c < NC) {
        const float4 r = reinterpret_cast<const float4*>(rel)[(size_t)row * NC + c];
        const float dx = r.x / 10.0f, dy = r.y / 10.0f;
        const float dw = fminf(r.z / 5.0f, 4.135166556742356f);
        const float dh = fminf(r.w / 5.0f, 4.135166556742356f);
        const float pcx = dx * w + cx, pcy = dy * h + cy;
        const float pw = expf(dw) * w, ph = expf(dh) * h;
        x1 = pcx - 0.5f * pw; y1 = pcy - 0.5f * ph;
        x2 = pcx + 0.5f * pw; y2 = pcy + 0.5f * ph;
        x1 = fminf(fmaxf(x1, 0.0f), 1333.0f);
        y1 = fminf(fmaxf(y1, 0.0f), 800.0f);
        x2 = fminf(fmaxf(x2, 0.0f), 1333.0f);
        y2 = fminf(fmaxf(y2, 0.0f), 800.0f);
        score = ev[j] / sum;
        const float localmax = fmaxf(fmaxf(x1, y1), fmaxf(x2, y2));
        tmax = max(tmax, __float_as_int(localmax));
        const float bw = x2 - x1, bh = y2 - y1;
        valid = (score > 0.05f) && (bw >= 0.01f) && (bh >= 0.01f);
      }
      const unsigned long long mk = __ballot(valid);
      if (valid) {
        const int leader = __ffsll(mk) - 1;
        const int rank = __popcll(mk & ((1ull << lane) - 1));
        int basel = 0;
        if (lane == leader) basel = atomicAdd(&scnt, __popcll(mk));
        basel = __shfl(basel, leader);
        const int slot = basel + rank;  // <= LCAP by the 19/row bound
        sbx[slot][0] = x1; sbx[slot][1] = y1;
        sbx[slot][2] = x2; sbx[slot][3] = y2;
        ssb[slot] = score;
        soidb[slot] = (row - b * NN) * CM1 + (c - 1);
      }
    }
  }
  tmax = max(tmax, __shfl_xor(tmax, 32));
  tmax = max(tmax, __shfl_xor(tmax, 16));
  tmax = max(tmax, __shfl_xor(tmax, 8));
  tmax = max(tmax, __shfl_xor(tmax, 4));
  tmax = max(tmax, __shfl_xor(tmax, 2));
  tmax = max(tmax, __shfl_xor(tmax, 1));
  if (lane == 0) atomicMax(&smaxs, tmax);
  __syncthreads();
  const int n = scnt;
  if (t == 0) {
    sgbase = atomicAdd(&ws_i[CNT_W(b)], n);
    atomicMax(&ws_i[MAX_W(b)], smaxs);
  }
  __syncthreads();
  const int gb = sgbase;
  for (int j = t; j < n; j += 256) {
    const int pos = gb + j;
    if (pos < GCAP) {
      reinterpret_cast<float4*>(ws_f + GBOX_OFF)[b * GCAP + pos] =
          make_float4(sbx[j][0], sbx[j][1], sbx[j][2], sbx[j][3]);
      ws_f[GSC_OFF + b * GCAP + pos] = ssb[j];
      ws_i[GOID_OFF + b * GCAP + pos] = soidb[j];
    }
  }
}

// Fused cooperative post-processing: hist -> gather -> matrix -> greedy,
// separated by grid syncs. 64 blocks (NB*GWB); matrix uses blocks <16,
// greedy blocks <4. Phase bodies are the round-17-proven kernels verbatim,
// LDS re-aliased per phase (race-free: full grid barrier between phases).
__global__ void __launch_bounds__(256) post_kernel(int* __restrict__ ws_i,
                                                   float* __restrict__ ws_f,
                                                   float* __restrict__ out) {
  cg::grid_group grid = cg::this_grid();
  const int t = threadIdx.x;
  const int lane = t & 63;
  __shared__ __align__(16) char sm[57344];
  __shared__ int sc_best1, sc_best2, sc_cA, sc_cR, sc_baseA, sc_baseR;
  __shared__ float4 selbox[100];
  __shared__ unsigned long long selkey[100];
  __shared__ int sellbl[100];
  __shared__ int selpos[100];
  __shared__ int s_cnt;
  __shared__ int snacc;

  // ---------------- phase 1: stripe-wise histogram ----------------
  {
    const int b = blockIdx.x / GWB, sub = blockIdx.x % GWB;
    int* lh = (int*)sm;  // 1024 ints
    for (int j = t; j < 1024; j += 256) lh[j] = 0;
    __syncthreads();
    int M = ws_i[CNT_W(b)];
    if (M > GCAP) M = GCAP;
    const float* gsc = ws_f + GSC_OFF + (size_t)b * GCAP;
    for (int j = sub * 256 + t; j < M; j += GWB * 256) {
      int bi = (int)(__float_as_uint(gsc[j]) >> 16) - 15360;
      bi = min(max(bi, 0), 1023);
      atomicAdd(&lh[bi], 1);
    }
    __syncthreads();
    for (int j = t; j < 1024; j += 256)
      if (lh[j]) atomicAdd(&ws_i[HIST_OFF + b * 1024 + j], lh[j]);
  }
  __threadfence();
  grid.sync();

  // ---------------- phase 2: gather (cutoff + classify) ----------------
  {
    const int b = blockIdx.x / GWB, sub = blockIdx.x % GWB;
    int* seg = (int*)sm;               // 256 ints
    int* lidxA = (int*)(sm + 1024);    // ACAP ints
    int* lidxR = (int*)(sm + 2048);    // CAP ints -> ends at 10240
    const int* H = ws_i + HIST_OFF + b * 1024;
    const int h0 = H[4 * t + 0], h1 = H[4 * t + 1];
    const int h2 = H[4 * t + 2], h3 = H[4 * t + 3];
    seg[t] = h0 + h1 + h2 + h3;
    if (t == 0) { sc_best1 = 1024; sc_best2 = 1024; sc_cA = 0; sc_cR = 0; }
    __syncthreads();
    for (int off = 1; off < 256; off <<= 1) {
      const int v = (t + off < 256) ? seg[t + off] : 0;
      __syncthreads();
      seg[t] += v;
      __syncthreads();
    }
    const int higher = (t < 255) ? seg[t + 1] : 0;
    {
      int A = higher; int cnd = 0x7FFFFFFF;
      A += h3; if (A <= CAP) cnd = 4 * t + 3;
      A += h2; if (A <= CAP) cnd = 4 * t + 2;
      A += h1; if (A <= CAP) cnd = 4 * t + 1;
      A += h0; if (A <= CAP) cnd = 4 * t + 0;
      if (cnd != 0x7FFFFFFF) atomicMin(&sc_best1, cnd);
    }
    {
      int A = higher; int cnd = 0x7FFFFFFF;
      A += h3; if (A <= ATHR) cnd = 4 * t + 3;
      A += h2; if (A <= ATHR) cnd = 4 * t + 2;
      A += h1; if (A <= ATHR) cnd = 4 * t + 1;
      A += h0; if (A <= ATHR) cnd = 4 * t + 0;
      if (cnd != 0x7FFFFFFF) atomicMin(&sc_best2, cnd);
    }
    __syncthreads();
    const int tk = sc_best1, tk2 = sc_best2;

    int M = ws_i[CNT_W(b)];
    if (M > GCAP) M = GCAP;
    const float* gsc = ws_f + GSC_OFF + (size_t)b * GCAP;
    const int* goid = ws_i + GOID_OFF + (size_t)b * GCAP;
    const float4* gbox = reinterpret_cast<const float4*>(ws_f + GBOX_OFF) + (size_t)b * GCAP;
    float4* abox = reinterpret_cast<float4*>(ws_f + ABOX_OFF) + (size_t)b * ACAP;
    unsigned long long* akey =
        reinterpret_cast<unsigned long long*>(ws_i + AKEY_OFF) + (size_t)b * ACAP;
    float4* rbox = reinterpret_cast<float4*>(ws_f + RBOX_OFF) + (size_t)b * CAP;
    unsigned long long* rkey =
        reinterpret_cast<unsigned long long*>(ws_i + RKEY_OFF) + (size_t)b * CAP;

    for (int j = sub * 256 + t; j < M; j += GWB * 256) {
      const float s = gsc[j];
      int bi = (int)(__float_as_uint(s) >> 16) - 15360;
      bi = min(max(bi, 0), 1023);
      if (bi >= tk2) {
        const int p = atomicAdd(&sc_cA, 1);
        if (p < ACAP) lidxA[p] = j;
      } else if (bi >= tk) {
        const int p = atomicAdd(&sc_cR, 1);
        if (p < CAP) lidxR[p] = j;
      }
    }
    __syncthreads();
    const int nAb = min(sc_cA, ACAP), nRb = min(sc_cR, CAP);
    if (t == 0) {
      sc_baseA = atomicAdd(&ws_i[CNTA_W(b)], nAb);
      sc_baseR = atomicAdd(&ws_i[CNTR_W(b)], nRb);
    }
    __syncthreads();
    for (int k = t; k < nAb; k += 256) {
      const int j = lidxA[k];
      const int pos = sc_baseA + k;
      if (pos < ACAP) {
        abox[pos] = gbox[j];
        akey[pos] = ((unsigned long long)(__float_as_uint(gsc[j]) | 0x80000000u) << 32) |
                    (unsigned)(0xFFFFFFFFu - (unsigned)goid[j]);
      }
    }
    for (int k = t; k < nRb; k += 256) {
      const int j = lidxR[k];
      const int pos = sc_baseR + k;
      if (pos < CAP) {
        rbox[pos] = gbox[j];
        rkey[pos] = ((unsigned long long)(__float_as_uint(gsc[j]) | 0x80000000u) << 32) |
                    (unsigned)(0xFFFFFFFFu - (unsigned)goid[j]);
      }
    }
  }
  __threadfence();
  grid.sync();

  // ---------------- phase 3: suppression matrix (blocks < 16) ----------------
  if (blockIdx.x < NB * MWB) {
    const int b = blockIdx.x / MWB, sub = blockIdx.x % MWB;
    unsigned long long* akey = (unsigned long long*)sm;           // 2KB @0
    float4* abox = (float4*)(sm + 2048);                          // 4KB
    unsigned long long* skeyS = (unsigned long long*)(sm + 6144); // 2KB
    float4* sboxS = (float4*)(sm + 8192);                         // 4KB
    int* slblS = (int*)(sm + 12288);                              // 1KB -> 13312

    const int nA = min(ws_i[CNTA_W(b)], ACAP);
    const float maxp1 = __int_as_float(ws_i[MAX_W(b)]) + 1.0f;
    const float4* gA = reinterpret_cast<const float4*>(ws_f + ABOX_OFF) + (size_t)b * ACAP;
    const unsigned long long* gAk =
        reinterpret_cast<const unsigned long long*>(ws_i + AKEY_OFF) + (size_t)b * ACAP;

    akey[t] = (t < nA) ? gAk[t] : 0ull;
    if (t < nA) abox[t] = gA[t];
    skeyS[t] = 0ull;
    sboxS[t] = make_float4(0.f, 0.f, 0.f, 0.f);
    slblS[t] = -1;
    __syncthreads();
    {
      const unsigned long long kj = akey[t];
      if (kj != 0ull) {
        int rank = 0;
#pragma unroll 16
        for (int i = 0; i < ACAP; ++i) rank += (akey[i] > kj) ? 1 : 0;
        skeyS[rank] = kj;
        sboxS[rank] = abox[t];
        const unsigned oid = 0xFFFFFFFFu - (unsigned)(kj & 0xFFFFFFFFull);
        slblS[rank] = (int)(oid % 90u) + 1;
      }
    }
    __syncthreads();

    if (sub == 0) {  // hand off sorted arrays to greedy
      reinterpret_cast<unsigned long long*>(ws_i + SKEY_OFF)[b * ACAP + t] = skeyS[t];
      reinterpret_cast<float4*>(ws_f + SBOX_OFF)[b * ACAP + t] = sboxS[t];
      ws_i[SLBL_OFF + b * ACAP + t] = slblS[t];
    }

    const int i = sub * 64 + (t >> 2);
    const int q = t & 3;
    const int li = slblS[i];
    const float4 bi = sboxS[i];
    const float oi = (float)li * maxp1;
    const float n0 = bi.x + oi, n1 = bi.y + oi;
    const float n2 = bi.z + oi, n3 = bi.w + oi;
    const float a1 = (n2 - n0) * (n3 - n1);
    unsigned long long r = 0;
#pragma unroll 8
    for (int k = 0; k < 64; ++k) {
      const int j = q * 64 + k;
      const int lj = slblS[j];
      const float4 bj = sboxS[j];
      const float q0 = bj.x + oi, q1 = bj.y + oi;
      const float q2 = bj.z + oi, q3 = bj.w + oi;
      const float ix1 = fmaxf(n0, q0), iy1 = fmaxf(n1, q1);
      const float ix2 = fminf(n2, q2), iy2 = fminf(n3, q3);
      const float inter = fmaxf(ix2 - ix1, 0.0f) * fmaxf(iy2 - iy1, 0.0f);
      const float a2 = (q2 - q0) * (q3 - q1);
      const float iou = inter / ((a1 + a2) - inter);
      const bool hit = (j > i) & (lj == li) & (iou > 0.5f);
      r |= hit ? (1ull << k) : 0ull;
    }
    unsigned long long* mtx =
        reinterpret_cast<unsigned long long*>(ws_i + MTX_OFF) + (size_t)b * 1024;
    mtx[i * 4 + q] = r;
  }
  __threadfence();
  grid.sync();

  // ---------------- phase 4: greedy (blocks < 4) ----------------
  if (blockIdx.x >= NB) return;
  {
    const int b = blockIdx.x;
    unsigned long long* skeyS = (unsigned long long*)sm;          // 2KB @0
    float4* sboxS = (float4*)(sm + 2048);                         // 4KB
    int* slblS = (int*)(sm + 6144);                               // 1KB
    unsigned long long* suppm = (unsigned long long*)(sm + 7168); // 8KB -> 15360
    float4* rboxS2 = (float4*)sm;                                 // fallback: 32KB @0
    unsigned long long* rkeyS2 = (unsigned long long*)(sm + 32768);// 16KB
    int* rlblS2 = (int*)(sm + 49152);                             // 8KB -> 57344

    const int nA = min(ws_i[CNTA_W(b)], ACAP);
    const int nR = min(ws_i[CNTR_W(b)], CAP);
    const float maxp1 = __int_as_float(ws_i[MAX_W(b)]) + 1.0f;
    const unsigned long long* mtx =
        reinterpret_cast<const unsigned long long*>(ws_i + MTX_OFF) + (size_t)b * 1024;

    skeyS[t] = reinterpret_cast<const unsigned long long*>(ws_i + SKEY_OFF)[b * ACAP + t];
    sboxS[t] = reinterpret_cast<const float4*>(ws_f + SBOX_OFF)[b * ACAP + t];
    slblS[t] = ws_i[SLBL_OFF + b * ACAP + t];
#pragma unroll
    for (int j2 = 0; j2 < 4; ++j2) suppm[j2 * 256 + t] = mtx[j2 * 256 + t];
    __syncthreads();

    if (t < 64) {
      unsigned long long m0 = 0, m1 = 0, m2 = 0, m3 = 0;
      int cnt = 0;
      int mypos0 = 0, mypos1 = 0;
#define NMS_CHUNK(W, MW)                                                  \
      if (cnt < 100 && (W)*64 < nA) {                                     \
        for (int base = 0; base < 64 && cnt < 100; base += 8) {           \
          unsigned long long sr0[8], sr1[8], sr2[8], sr3[8];              \
          _Pragma("unroll")                                               \
          for (int k = 0; k < 8; ++k) {                                   \
            const int j = (W) * 64 + base + k;                            \
            sr0[k] = suppm[j * 4 + 0];                                    \
            sr1[k] = suppm[j * 4 + 1];                                    \
            sr2[k] = suppm[j * 4 + 2];                                    \
            sr3[k] = suppm[j * 4 + 3];                                    \
          }                                                               \
          _Pragma("unroll")                                               \
          for (int k = 0; k < 8; ++k) {                                   \
            const int j = (W) * 64 + base + k;                            \
            const bool acc =                                              \
                (j < nA) && (cnt < 100) && !((MW >> (base + k)) & 1ull);  \
            if (acc) {                                                    \
              if (cnt == lane) mypos0 = j;                                \
              if (cnt == 64 + lane) mypos1 = j;                           \
              ++cnt;                                                      \
              m0 |= sr0[k]; m1 |= sr1[k]; m2 |= sr2[k]; m3 |= sr3[k];     \
            }                                                             \
          }                                                               \
        }                                                                 \
      }
      NMS_CHUNK(0, m0)
      NMS_CHUNK(1, m1)
      NMS_CHUNK(2, m2)
      NMS_CHUNK(3, m3)
#undef NMS_CHUNK
      selpos[lane] = mypos0;
      if (lane < 36) selpos[64 + lane] = mypos1;
      if (lane == 0) s_cnt = cnt;
    }
    __syncthreads();
    const int cnt = s_cnt;

    if (cnt >= 100 || nR == 0) {
      const int nf = min(cnt, 100);
      if (t < 100) {
        float o0 = 0.f, o1 = 0.f, o2 = 0.f, o3 = 0.f, sc = 0.f, lb = 0.f;
        if (t < nf) {
          const int mypos = selpos[t];
          const float4 v = sboxS[mypos];
          o0 = v.x; o1 = v.y; o2 = v.z; o3 = v.w;
          sc = __uint_as_float((unsigned)(skeyS[mypos] >> 32) & 0x7FFFFFFFu);
          lb = (float)slblS[mypos];
        }
        float* ob = out + ((size_t)b * 100 + t) * 4;
        ob[0] = o0; ob[1] = o1; ob[2] = o2; ob[3] = o3;
        out[NB * 100 * 4 + b * 100 + t] = sc;
        out[NB * 100 * 4 + NB * 100 + b * 100 + t] = lb;
      }
      return;
    }

    // ---- fallback (normally never taken): exact sequential + reserve ----
    float A0x = 0.f, A0y = 0.f, A0z = 0.f, A0w = 0.f; int L0 = -1;
    float A1x = 0.f, A1y = 0.f, A1z = 0.f, A1w = 0.f; int L1 = -1;
    int nacc = 0;

    if (t < 64) {
      unsigned long long k0 = skeyS[0], k1 = skeyS[1];
      float4 b0 = sboxS[0], b1 = sboxS[1];
      int l0 = slblS[0], l1 = slblS[1];
      for (int j = 0; j < ACAP; ++j) {
        if (k0 == 0ull) break;
        const int jp = j + 2;
        unsigned long long k2 = 0ull;
        float4 b2 = make_float4(0.f, 0.f, 0.f, 0.f);
        int l2 = 0;
        if (jp < ACAP) { k2 = skeyS[jp]; b2 = sboxS[jp]; l2 = slblS[jp]; }
        const float oi = (float)l0 * maxp1;
        const float q0 = b0.x + oi, q1 = b0.y + oi;
        const float q2 = b0.z + oi, q3 = b0.w + oi;
        const float a2 = (q2 - q0) * (q3 - q1);
        bool sup = false;
        if (L0 == l0) {
          const float n0 = A0x + oi, n1 = A0y + oi, n2 = A0z + oi, n3 = A0w + oi;
          const float a1 = (n2 - n0) * (n3 - n1);
          const float ix1 = fmaxf(n0, q0), iy1 = fmaxf(n1, q1);
          const float ix2 = fminf(n2, q2), iy2 = fminf(n3, q3);
          const float inter = fmaxf(ix2 - ix1, 0.0f) * fmaxf(iy2 - iy1, 0.0f);
          const float iou = inter / ((a1 + a2) - inter);
          sup = (iou > 0.5f);
        }
        if (L1 == l0) {
          const float n0 = A1x + oi, n1 = A1y + oi, n2 = A1z + oi, n3 = A1w + oi;
          const float a1 = (n2 - n0) * (n3 - n1);
          const float ix1 = fmaxf(n0, q0), iy1 = fmaxf(n1, q1);
          const float ix2 = fminf(n2, q2), iy2 = fminf(n3, q3);
          const float inter = fmaxf(ix2 - ix1, 0.0f) * fmaxf(iy2 - iy1, 0.0f);
          const float iou = inter / ((a1 + a2) - inter);
          sup = sup || (iou > 0.5f);
        }
        if (!__any(sup ? 1 : 0)) {
          if (nacc < 64) {
            if (lane == nacc) { A0x = b0.x; A0y = b0.y; A0z = b0.z; A0w = b0.w; L0 = l0; }
          } else {
            if (lane == nacc - 64) { A1x = b0.x; A1y = b0.y; A1z = b0.z; A1w = b0.w; L1 = l0; }
          }
          if (lane == 0) { selbox[nacc] = b0; selkey[nacc] = k0; sellbl[nacc] = l0; }
          ++nacc;
          if (nacc == 100) break;
        }
        k0 = k1; b0 = b1; l0 = l1;
        k1 = k2; b1 = b2; l1 = l2;
      }
      if (lane == 0) snacc = nacc;
    }
    __syncthreads();

    if (snacc < 100 && nR > 0) {
      const float4* gR = reinterpret_cast<const float4*>(ws_f + RBOX_OFF) + (size_t)b * CAP;
      const unsigned long long* gRk =
          reinterpret_cast<const unsigned long long*>(ws_i + RKEY_OFF) + (size_t)b * CAP;
      for (int j = t; j < CAP; j += 256) {
        const unsigned long long k = (j < nR) ? gRk[j] : 0ull;
        rkeyS2[j] = k;
        if (j < nR) {
          rboxS2[j] = gR[j];
          const unsigned oid = 0xFFFFFFFFu - (unsigned)(k & 0xFFFFFFFFull);
          rlblS2[j] = (int)(oid % 90u) + 1;
        }
      }
      __syncthreads();
      if (t < 64) {
        while (nacc < 100) {
          unsigned long long mk = 0ull; int mi = 0;
          for (int j = lane; j < nR; j += 64) {
            const unsigned long long k = rkeyS2[j];
            if (k > mk) { mk = k; mi = j; }
          }
          for (int mm = 1; mm < 64; mm <<= 1) {
            const unsigned long long ok = __shfl_xor(mk, mm);
            const int om = __shfl_xor(mi, mm);
            if (ok > mk) { mk = ok; mi = om; }
          }
          if (mk == 0ull) break;
          if (lane == 0) rkeyS2[mi] = 0ull;
          __asm__ volatile("s_waitcnt lgkmcnt(0)" ::: "memory");
          const int lbl = rlblS2[mi];
          const float4 bb = rboxS2[mi];
          const float oi = (float)lbl * maxp1;
          const float q0 = bb.x + oi, q1 = bb.y + oi;
          const float q2 = bb.z + oi, q3 = bb.w + oi;
          const float a2 = (q2 - q0) * (q3 - q1);
          bool sup = false;
          if (L0 == lbl) {
            const float n0 = A0x + oi, n1 = A0y + oi, n2 = A0z + oi, n3 = A0w + oi;
            const float a1 = (n2 - n0) * (n3 - n1);
            const float ix1 = fmaxf(n0, q0), iy1 = fmaxf(n1, q1);
            const float ix2 = fminf(n2, q2), iy2 = fminf(n3, q3);
            const float inter = fmaxf(ix2 - ix1, 0.0f) * fmaxf(iy2 - iy1, 0.0f);
            const float iou = inter / ((a1 + a2) - inter);
            sup = (iou > 0.5f);
          }
          if (L1 == lbl) {
            const float n0 = A1x + oi, n1 = A1y + oi, n2 = A1z + oi, n3 = A1w + oi;
            const float a1 = (n2 - n0) * (n3 - n1);
            const float ix1 = fmaxf(n0, q0), iy1 = fmaxf(n1, q1);
            const float ix2 = fminf(n2, q2), iy2 = fminf(n3, q3);
            const float inter = fmaxf(ix2 - ix1, 0.0f) * fmaxf(iy2 - iy1, 0.0f);
            const float iou = inter / ((a1 + a2) - inter);
            sup = sup || (iou > 0.5f);
          }
          if (!__any(sup ? 1 : 0)) {
            if (nacc < 64) {
              if (lane == nacc) { A0x = bb.x; A0y = bb.y; A0z = bb.z; A0w = bb.w; L0 = lbl; }
            } else {
              if (lane == nacc - 64) { A1x = bb.x; A1y = bb.y; A1z = bb.z; A1w = bb.w; L1 = lbl; }
            }
            if (lane == 0) { selbox[nacc] = bb; selkey[nacc] = mk; sellbl[nacc] = lbl; }
            ++nacc;
          }
        }
        if (lane == 0) snacc = nacc;
      }
      __syncthreads();
    }

    const int nf = snacc;
    for (int k2 = t; k2 < 100; k2 += 256) {
      float o0 = 0.f, o1 = 0.f, o2 = 0.f, o3 = 0.f, sc = 0.f, lb = 0.f;
      if (k2 < nf) {
        const float4 v = selbox[k2];
        o0 = v.x; o1 = v.y; o2 = v.z; o3 = v.w;
        sc = __uint_as_float((unsigned)(selkey[k2] >> 32) & 0x7FFFFFFFu);
        lb = (float)sellbl[k2];
      }
      float* ob = out + ((size_t)b * 100 + k2) * 4;
      ob[0] = o0; ob[1] = o1; ob[2] = o2; ob[3] = o3;
      out[NB * 100 * 4 + b * 100 + k2] = sc;
      out[NB * 100 * 4 + NB * 100 + b * 100 + k2] = lb;
    }
  }
}

extern "C" void kernel_launch(void* const* d_in, const int* in_sizes, int n_in,
                              void* d_out, int out_size, void* d_ws, size_t ws_size,
                              hipStream_t stream) {
  const float* logits = (const float*)d_in[0];
  const float* rel = (const float*)d_in[1];
  const float* props = (const float*)d_in[2];
  float* out = (float*)d_out;
  int* ws_i = (int*)d_ws;
  float* ws_f = (float*)d_ws;

  hipMemsetAsync(d_ws, 0, (size_t)ZERO_WORDS * 4, stream);
  cand_kernel<<<NB * BPI, 256, 0, stream>>>(logits, rel, props, ws_i, ws_f);
  void* args[] = {(void*)&ws_i, (void*)&ws_f, (void*)&out};
  hipLaunchCooperativeKernel((const void*)post_kernel, dim3(NB * GWB), dim3(256),
                             args, 0, stream);
}

// Round 19
// 67.901 us; speedup vs baseline: 1.6704x; 1.6704x over previous
//
#include <hip/hip_runtime.h>
#include <math.h>

#pragma clang fp contract(off)

#define NB 4
#define NN 8000
#define NC 91
#define CM1 90
#define CAP 2048          // outer kept bound (proven sufficient rounds 1-18)
#define ACAP 256          // chunk-A padded size
#define ATHR 192          // chunk-A histogram bound
#define GCAP 65536
#define RPB 32            // rows per block in cand_kernel
#define BPI (NN / RPB)    // 250 blocks per image
#define LCAP 608          // = RPB*19 (hard bound: <=19 scores>0.05 per row)
#define GWB 16            // wide blocks per image for hist/gather
#define MWB 4             // matrix sub-blocks per image (64 rows each)

// ws layout (32-bit words). Hot counters padded: one 256B line per counter
// per image (round-10 lesson: same-line cross-XCD atomics cost ~13ns each).
#define CNT_W(b) ((b) * 64)          // valid count
#define MAX_W(b) (256 + (b) * 64)    // coord-max bits
#define CNTA_W(b) (512 + (b) * 64)
#define CNTR_W(b) (768 + (b) * 64)
#define HIST_OFF 1024                // NB*1024 global hist
#define ZERO_WORDS (HIST_OFF + NB * 1024)   // 5120
#define GBOX_OFF 5120                        // NB*GCAP float4 (16B aligned)
#define GSC_OFF (GBOX_OFF + NB * GCAP * 4)
#define GOID_OFF (GSC_OFF + NB * GCAP)
#define ABOX_OFF (GOID_OFF + NB * GCAP)      // NB*ACAP float4
#define AKEY_OFF (ABOX_OFF + NB * ACAP * 4)  // NB*ACAP u64
#define RBOX_OFF (AKEY_OFF + NB * ACAP * 2)  // NB*CAP float4
#define RKEY_OFF (RBOX_OFF + NB * CAP * 4)   // NB*CAP u64
#define MTX_OFF (RKEY_OFF + NB * CAP * 2)    // NB*1024 u64 (suppression matrix)
#define SKEY_OFF (MTX_OFF + NB * 2048)       // NB*256 u64 sorted keys
#define SBOX_OFF (SKEY_OFF + NB * 512)       // NB*256 float4 sorted boxes
#define SLBL_OFF (SBOX_OFF + NB * 1024)      // NB*256 int sorted labels

// cand (round-15/16/17-proven): 16 lanes/row, in-register softmax tree +
// 4 shfl_xor, wave-aggregated ballot compaction, padded global counters.
__global__ void __launch_bounds__(256) cand_kernel(const float* __restrict__ logits,
                                                   const float* __restrict__ rel,
                                                   const float* __restrict__ props,
                                                   int* __restrict__ ws_i,
                                                   float* __restrict__ ws_f) {
  const int blk = blockIdx.x;
  const int b = blk / BPI;
  const int ib = blk - b * BPI;
  const int t = threadIdx.x;
  const int L = t & 15;      // lane within 16-lane row group
  const int grp = t >> 4;    // 0..15
  const int lane = t & 63;

  __shared__ float sbx[LCAP][4];
  __shared__ float ssb[LCAP];
  __shared__ int soidb[LCAP];
  __shared__ int scnt;
  __shared__ int smaxs;
  __shared__ int sgbase;
  if (t == 0) { scnt = 0; smaxs = 0; }
  __syncthreads();

  int tmax = 0;  // thread-local coord max (float bits; coords >= 0)

  for (int i = 0; i < RPB / 16; ++i) {
    const int row = b * NN + ib * RPB + i * 16 + grp;
    const float* lp = logits + (size_t)row * NC;

    float lv[6];
#pragma unroll
    for (int j = 0; j < 6; ++j) {
      const int k = L + 16 * j;
      lv[j] = (k < NC) ? lp[k] : -INFINITY;
    }
    float tm0 = fmax(lv[0], lv[4]), tm1 = fmax(lv[1], lv[5]);
    float tm2 = lv[2], tm3 = lv[3];
    float um0 = fmax(tm0, tm2), um1 = fmax(tm1, tm3);
    float m = fmax(um0, um1);
    m = fmaxf(m, __shfl_xor(m, 8));
    m = fmaxf(m, __shfl_xor(m, 4));
    m = fmaxf(m, __shfl_xor(m, 2));
    m = fmaxf(m, __shfl_xor(m, 1));

    float ev[6];
#pragma unroll
    for (int j = 0; j < 6; ++j) {
      const int k = L + 16 * j;
      ev[j] = (k < NC) ? expf(lv[j] - m) : 0.0f;
    }
    float ts0 = ev[0] + ev[4], ts1 = ev[1] + ev[5];
    float ts2 = ev[2], ts3 = ev[3];
    float us0 = ts0 + ts2, us1 = ts1 + ts3;
    float sum = us0 + us1;
    sum += __shfl_xor(sum, 8);
    sum += __shfl_xor(sum, 4);
    sum += __shfl_xor(sum, 2);
    sum += __shfl_xor(sum, 1);

    const float4 p = reinterpret_cast<const float4*>(props)[row];
    const float w = p.z - p.x, h = p.w - p.y;
    const float cx = p.x + 0.5f * w, cy = p.y + 0.5f * h;

#pragma unroll
    for (int j = 0; j < 6; ++j) {
      const int c = L + 16 * j;
      bool valid = false;
      float x1 = 0.f, y1 = 0.f, x2 = 0.f, y2 = 0.f, score = 0.f;
      if (c >= 1 && c < NC) {
        const float4 r = reinterpret_cast<const float4*>(rel)[(size_t)row * NC + c];
        const float dx = r.x / 10.0f, dy = r.y / 10.0f;
        const float dw = fminf(r.z / 5.0f, 4.135166556742356f);
        const float dh = fminf(r.w / 5.0f, 4.135166556742356f);
        const float pcx = dx * w + cx, pcy = dy * h + cy;
        const float pw = expf(dw) * w, ph = expf(dh) * h;
        x1 = pcx - 0.5f * pw; y1 = pcy - 0.5f * ph;
        x2 = pcx + 0.5f * pw; y2 = pcy + 0.5f * ph;
        x1 = fminf(fmaxf(x1, 0.0f), 1333.0f);
        y1 = fminf(fmaxf(y1, 0.0f), 800.0f);
        x2 = fminf(fmaxf(x2, 0.0f), 1333.0f);
        y2 = fminf(fmaxf(y2, 0.0f), 800.0f);
        score = ev[j] / sum;
        const float localmax = fmaxf(fmaxf(x1, y1), fmaxf(x2, y2));
        tmax = max(tmax, __float_as_int(localmax));
        const float bw = x2 - x1, bh = y2 - y1;
        valid = (score > 0.05f) && (bw >= 0.01f) && (bh >= 0.01f);
      }
      const unsigned long long mk = __ballot(valid);
      if (valid) {
        const int leader = __ffsll(mk) - 1;
        const int rank = __popcll(mk & ((1ull << lane) - 1));
        int basel = 0;
        if (lane == leader) basel = atomicAdd(&scnt, __popcll(mk));
        basel = __shfl(basel, leader);
        const int slot = basel + rank;  // <= LCAP by the 19/row bound
        sbx[slot][0] = x1; sbx[slot][1] = y1;
        sbx[slot][2] = x2; sbx[slot][3] = y2;
        ssb[slot] = score;
        soidb[slot] = (row - b * NN) * CM1 + (c - 1);
      }
    }
  }
  tmax = max(tmax, __shfl_xor(tmax, 32));
  tmax = max(tmax, __shfl_xor(tmax, 16));
  tmax = max(tmax, __shfl_xor(tmax, 8));
  tmax = max(tmax, __shfl_xor(tmax, 4));
  tmax = max(tmax, __shfl_xor(tmax, 2));
  tmax = max(tmax, __shfl_xor(tmax, 1));
  if (lane == 0) atomicMax(&smaxs, tmax);
  __syncthreads();
  const int n = scnt;
  if (t == 0) {
    sgbase = atomicAdd(&ws_i[CNT_W(b)], n);
    atomicMax(&ws_i[MAX_W(b)], smaxs);
  }
  __syncthreads();
  const int gb = sgbase;
  for (int j = t; j < n; j += 256) {
    const int pos = gb + j;
    if (pos < GCAP) {
      reinterpret_cast<float4*>(ws_f + GBOX_OFF)[b * GCAP + pos] =
          make_float4(sbx[j][0], sbx[j][1], sbx[j][2], sbx[j][3]);
      ws_f[GSC_OFF + b * GCAP + pos] = ssb[j];
      ws_i[GOID_OFF + b * GCAP + pos] = soidb[j];
    }
  }
}

// Dedicated stripe-wise histogram (round-9-proven): block (b,sub) histograms
// ONLY its 1/16 stripe into LDS, then merges 1024 bins to the global hist.
__global__ void __launch_bounds__(256) hist_kernel(int* __restrict__ ws_i,
                                                   const float* __restrict__ ws_f) {
  const int b = blockIdx.x / GWB, sub = blockIdx.x % GWB;
  const int t = threadIdx.x;
  __shared__ int lh[1024];
  for (int j = t; j < 1024; j += 256) lh[j] = 0;
  __syncthreads();
  int M = ws_i[CNT_W(b)];
  if (M > GCAP) M = GCAP;
  const float* gsc = ws_f + GSC_OFF + (size_t)b * GCAP;
  for (int j = sub * 256 + t; j < M; j += GWB * 256) {
    int bi = (int)(__float_as_uint(gsc[j]) >> 16) - 15360;
    bi = min(max(bi, 0), 1023);
    atomicAdd(&lh[bi], 1);
  }
  __syncthreads();
  for (int j = t; j < 1024; j += 256)
    if (lh[j]) atomicAdd(&ws_i[HIST_OFF + b * 1024 + j], lh[j]);
}

// Wide gather: reads the global hist, computes tk/tk2, classifies its stripe
// via LDS index lists + ONE global atomicAdd per list per block.
__global__ void __launch_bounds__(256) gather_kernel(int* __restrict__ ws_i,
                                                     float* __restrict__ ws_f) {
  const int b = blockIdx.x / GWB, sub = blockIdx.x % GWB;
  const int t = threadIdx.x;
  __shared__ int seg[256];
  __shared__ int best1, best2;
  __shared__ int lidxA[ACAP];   // total A <= ATHR=192 by cutoff construction
  __shared__ int lidxR[CAP];    // total R <= CAP by cutoff construction
  __shared__ int cA, cR, baseA, baseR;

  const int* H = ws_i + HIST_OFF + b * 1024;
  const int h0 = H[4 * t + 0], h1 = H[4 * t + 1];
  const int h2 = H[4 * t + 2], h3 = H[4 * t + 3];
  seg[t] = h0 + h1 + h2 + h3;
  if (t == 0) { best1 = 1024; best2 = 1024; cA = 0; cR = 0; }
  __syncthreads();
  for (int off = 1; off < 256; off <<= 1) {
    const int v = (t + off < 256) ? seg[t + off] : 0;
    __syncthreads();
    seg[t] += v;
    __syncthreads();
  }
  const int higher = (t < 255) ? seg[t + 1] : 0;
  {
    int A = higher; int cnd = 0x7FFFFFFF;
    A += h3; if (A <= CAP) cnd = 4 * t + 3;
    A += h2; if (A <= CAP) cnd = 4 * t + 2;
    A += h1; if (A <= CAP) cnd = 4 * t + 1;
    A += h0; if (A <= CAP) cnd = 4 * t + 0;
    if (cnd != 0x7FFFFFFF) atomicMin(&best1, cnd);
  }
  {
    int A = higher; int cnd = 0x7FFFFFFF;
    A += h3; if (A <= ATHR) cnd = 4 * t + 3;
    A += h2; if (A <= ATHR) cnd = 4 * t + 2;
    A += h1; if (A <= ATHR) cnd = 4 * t + 1;
    A += h0; if (A <= ATHR) cnd = 4 * t + 0;
    if (cnd != 0x7FFFFFFF) atomicMin(&best2, cnd);
  }
  __syncthreads();
  const int tk = best1, tk2 = best2;

  int M = ws_i[CNT_W(b)];
  if (M > GCAP) M = GCAP;
  const float* gsc = ws_f + GSC_OFF + (size_t)b * GCAP;
  const int* goid = ws_i + GOID_OFF + (size_t)b * GCAP;
  const float4* gbox = reinterpret_cast<const float4*>(ws_f + GBOX_OFF) + (size_t)b * GCAP;
  float4* abox = reinterpret_cast<float4*>(ws_f + ABOX_OFF) + (size_t)b * ACAP;
  unsigned long long* akey = reinterpret_cast<unsigned long long*>(ws_i + AKEY_OFF) + (size_t)b * ACAP;
  float4* rbox = reinterpret_cast<float4*>(ws_f + RBOX_OFF) + (size_t)b * CAP;
  unsigned long long* rkey = reinterpret_cast<unsigned long long*>(ws_i + RKEY_OFF) + (size_t)b * CAP;

  for (int j = sub * 256 + t; j < M; j += GWB * 256) {
    const float s = gsc[j];
    int bi = (int)(__float_as_uint(s) >> 16) - 15360;
    bi = min(max(bi, 0), 1023);
    if (bi >= tk2) {
      const int p = atomicAdd(&cA, 1);
      if (p < ACAP) lidxA[p] = j;
    } else if (bi >= tk) {
      const int p = atomicAdd(&cR, 1);
      if (p < CAP) lidxR[p] = j;
    }
  }
  __syncthreads();
  const int nAb = min(cA, ACAP), nRb = min(cR, CAP);
  if (t == 0) {
    baseA = atomicAdd(&ws_i[CNTA_W(b)], nAb);
    baseR = atomicAdd(&ws_i[CNTR_W(b)], nRb);
  }
  __syncthreads();
  for (int k = t; k < nAb; k += 256) {
    const int j = lidxA[k];
    const int pos = baseA + k;
    if (pos < ACAP) {
      abox[pos] = gbox[j];
      akey[pos] = ((unsigned long long)(__float_as_uint(gsc[j]) | 0x80000000u) << 32) |
                  (unsigned)(0xFFFFFFFFu - (unsigned)goid[j]);
    }
  }
  for (int k = t; k < nRb; k += 256) {
    const int j = lidxR[k];
    const int pos = baseR + k;
    if (pos < CAP) {
      rbox[pos] = gbox[j];
      rkey[pos] = ((unsigned long long)(__float_as_uint(gsc[j]) | 0x80000000u) << 32) |
                  (unsigned)(0xFFFFFFFFu - (unsigned)goid[j]);
    }
  }
}

// Wide suppression matrix: block (b,sub) computes rows [64*sub, 64*sub+64).
// Redundant per-block rank-sort (deterministic: keys unique). sub==0 also
// writes the sorted arrays to ws so greedy can skip its own sort.
__global__ void __launch_bounds__(256) matrix_kernel(const int* __restrict__ ws_i,
                                                     const float* __restrict__ ws_f,
                                                     int* __restrict__ ws_o,
                                                     float* __restrict__ ws_of) {
  const int b = blockIdx.x / MWB, sub = blockIdx.x % MWB;
  const int t = threadIdx.x;
  __shared__ unsigned long long akey[ACAP];
  __shared__ float4 abox[ACAP];
  __shared__ unsigned long long skeyS[ACAP];
  __shared__ float4 sboxS[ACAP];
  __shared__ int slblS[ACAP];

  const int nA = min(ws_i[CNTA_W(b)], ACAP);
  const float maxp1 = __int_as_float(ws_i[MAX_W(b)]) + 1.0f;
  const float4* gA = reinterpret_cast<const float4*>(ws_f + ABOX_OFF) + (size_t)b * ACAP;
  const unsigned long long* gAk =
      reinterpret_cast<const unsigned long long*>(ws_i + AKEY_OFF) + (size_t)b * ACAP;

  akey[t] = (t < nA) ? gAk[t] : 0ull;
  if (t < nA) abox[t] = gA[t];
  skeyS[t] = 0ull;
  sboxS[t] = make_float4(0.f, 0.f, 0.f, 0.f);
  slblS[t] = -1;
  __syncthreads();
  {
    const unsigned long long kj = akey[t];
    if (kj != 0ull) {
      int rank = 0;
#pragma unroll 16
      for (int i = 0; i < ACAP; ++i) rank += (akey[i] > kj) ? 1 : 0;
      skeyS[rank] = kj;
      sboxS[rank] = abox[t];
      const unsigned oid = 0xFFFFFFFFu - (unsigned)(kj & 0xFFFFFFFFull);
      slblS[rank] = (int)(oid % 90u) + 1;
    }
  }
  __syncthreads();

  if (sub == 0) {  // hand off sorted arrays to greedy
    reinterpret_cast<unsigned long long*>(ws_o + SKEY_OFF)[b * ACAP + t] = skeyS[t];
    reinterpret_cast<float4*>(ws_of + SBOX_OFF)[b * ACAP + t] = sboxS[t];
    ws_o[SLBL_OFF + b * ACAP + t] = slblS[t];
  }

  const int i = sub * 64 + (t >> 2);
  const int q = t & 3;
  const int li = slblS[i];
  const float4 bi = sboxS[i];
  const float oi = (float)li * maxp1;
  const float n0 = bi.x + oi, n1 = bi.y + oi;
  const float n2 = bi.z + oi, n3 = bi.w + oi;
  const float a1 = (n2 - n0) * (n3 - n1);
  unsigned long long r = 0;
#pragma unroll 8
  for (int k = 0; k < 64; ++k) {
    const int j = q * 64 + k;
    const int lj = slblS[j];
    const float4 bj = sboxS[j];
    const float q0 = bj.x + oi, q1 = bj.y + oi;
    const float q2 = bj.z + oi, q3 = bj.w + oi;
    const float ix1 = fmaxf(n0, q0), iy1 = fmaxf(n1, q1);
    const float ix2 = fminf(n2, q2), iy2 = fminf(n3, q3);
    const float inter = fmaxf(ix2 - ix1, 0.0f) * fmaxf(iy2 - iy1, 0.0f);
    const float a2 = (q2 - q0) * (q3 - q1);
    const float iou = inter / ((a1 + a2) - inter);
    const bool hit = (j > i) & (lj == li) & (iou > 0.5f);
    r |= hit ? (1ull << k) : 0ull;
  }
  unsigned long long* mtx =
      reinterpret_cast<unsigned long long*>(ws_o + MTX_OFF) + (size_t)b * 1024;
  mtx[i * 4 + q] = r;   // = mtx[sub*256 + t]: coalesced
}

// One block per image: load SORTED arrays + matrix (no sort), single-wave
// greedy bitmask scan; exact sequential+reserve fallback (normally not taken).
__global__ void __launch_bounds__(256) greedy_kernel(const int* __restrict__ ws_i,
                                                     const float* __restrict__ ws_f,
                                                     float* __restrict__ out) {
  const int b = blockIdx.x;
  const int t = threadIdx.x;
  const int lane = t & 63;
  __shared__ __align__(16) char sm[57344];
  unsigned long long* skeyS = (unsigned long long*)sm;           // 256 u64: 0..2048
  float4* sboxS = (float4*)(sm + 2048);                          // 256 f4: ..6144
  int* slblS = (int*)(sm + 6144);                                // 256 int: ..7168
  unsigned long long* suppm = (unsigned long long*)(sm + 7168);  // 256x4 u64: ..15360
  // fallback phase (sorted arrays + suppm dead by then): disjoint-by-phase
  float4* rboxS2 = (float4*)sm;                                  // 2048 f4: 0..32768
  unsigned long long* rkeyS2 = (unsigned long long*)(sm + 32768);// 2048 u64: ..49152
  int* rlblS2 = (int*)(sm + 49152);                              // 2048 int: ..57344
  __shared__ float4 selbox[100];
  __shared__ unsigned long long selkey[100];
  __shared__ int sellbl[100];
  __shared__ int selpos[100];
  __shared__ int s_cnt;
  __shared__ int snacc;

  const int nA = min(ws_i[CNTA_W(b)], ACAP);
  const int nR = min(ws_i[CNTR_W(b)], CAP);
  const float maxp1 = __int_as_float(ws_i[MAX_W(b)]) + 1.0f;
  const unsigned long long* mtx =
      reinterpret_cast<const unsigned long long*>(ws_i + MTX_OFF) + (size_t)b * 1024;

  skeyS[t] = reinterpret_cast<const unsigned long long*>(ws_i + SKEY_OFF)[b * ACAP + t];
  sboxS[t] = reinterpret_cast<const float4*>(ws_f + SBOX_OFF)[b * ACAP + t];
  slblS[t] = ws_i[SLBL_OFF + b * ACAP + t];
#pragma unroll
  for (int j2 = 0; j2 < 4; ++j2) suppm[j2 * 256 + t] = mtx[j2 * 256 + t];
  __syncthreads();

  // --- single-wave greedy bitmask scan, batched row loads ---
  if (t < 64) {
    unsigned long long m0 = 0, m1 = 0, m2 = 0, m3 = 0;
    int cnt = 0;
    int mypos0 = 0, mypos1 = 0;
#define NMS_CHUNK(W, MW)                                                  \
    if (cnt < 100 && (W)*64 < nA) {                                       \
      for (int base = 0; base < 64 && cnt < 100; base += 8) {             \
        unsigned long long sr0[8], sr1[8], sr2[8], sr3[8];                \
        _Pragma("unroll")                                                 \
        for (int k = 0; k < 8; ++k) {                                     \
          const int j = (W) * 64 + base + k;                              \
          sr0[k] = suppm[j * 4 + 0];                                      \
          sr1[k] = suppm[j * 4 + 1];                                      \
          sr2[k] = suppm[j * 4 + 2];                                      \
          sr3[k] = suppm[j * 4 + 3];                                      \
        }                                                                 \
        _Pragma("unroll")                                                 \
        for (int k = 0; k < 8; ++k) {                                     \
          const int j = (W) * 64 + base + k;                              \
          const bool acc =                                                \
              (j < nA) && (cnt < 100) && !((MW >> (base + k)) & 1ull);    \
          if (acc) {                                                      \
            if (cnt == lane) mypos0 = j;                                  \
            if (cnt == 64 + lane) mypos1 = j;                             \
            ++cnt;                                                        \
            m0 |= sr0[k]; m1 |= sr1[k]; m2 |= sr2[k]; m3 |= sr3[k];       \
          }                                                               \
        }                                                                 \
      }                                                                   \
    }
    NMS_CHUNK(0, m0)
    NMS_CHUNK(1, m1)
    NMS_CHUNK(2, m2)
    NMS_CHUNK(3, m3)
#undef NMS_CHUNK
    selpos[lane] = mypos0;
    if (lane < 36) selpos[64 + lane] = mypos1;
    if (lane == 0) s_cnt = cnt;
  }
  __syncthreads();
  const int cnt = s_cnt;

  if (cnt >= 100 || nR == 0) {
    const int nf = min(cnt, 100);
    if (t < 100) {
      float o0 = 0.f, o1 = 0.f, o2 = 0.f, o3 = 0.f, sc = 0.f, lb = 0.f;
      if (t < nf) {
        const int mypos = selpos[t];
        const float4 v = sboxS[mypos];
        o0 = v.x; o1 = v.y; o2 = v.z; o3 = v.w;
        sc = __uint_as_float((unsigned)(skeyS[mypos] >> 32) & 0x7FFFFFFFu);
        lb = (float)slblS[mypos];
      }
      float* ob = out + ((size_t)b * 100 + t) * 4;
      ob[0] = o0; ob[1] = o1; ob[2] = o2; ob[3] = o3;
      out[NB * 100 * 4 + b * 100 + t] = sc;
      out[NB * 100 * 4 + NB * 100 + b * 100 + t] = lb;
    }
    return;
  }

  // ---- fallback (normally never taken): exact sequential + reserve ----
  float A0x = 0.f, A0y = 0.f, A0z = 0.f, A0w = 0.f; int L0 = -1;
  float A1x = 0.f, A1y = 0.f, A1z = 0.f, A1w = 0.f; int L1 = -1;
  int nacc = 0;

  if (t < 64) {
    unsigned long long k0 = skeyS[0], k1 = skeyS[1];
    float4 b0 = sboxS[0], b1 = sboxS[1];
    int l0 = slblS[0], l1 = slblS[1];
    for (int j = 0; j < ACAP; ++j) {
      if (k0 == 0ull) break;
      const int jp = j + 2;
      unsigned long long k2 = 0ull;
      float4 b2 = make_float4(0.f, 0.f, 0.f, 0.f);
      int l2 = 0;
      if (jp < ACAP) { k2 = skeyS[jp]; b2 = sboxS[jp]; l2 = slblS[jp]; }
      const float oi = (float)l0 * maxp1;
      const float q0 = b0.x + oi, q1 = b0.y + oi;
      const float q2 = b0.z + oi, q3 = b0.w + oi;
      const float a2 = (q2 - q0) * (q3 - q1);
      bool sup = false;
      if (L0 == l0) {
        const float n0 = A0x + oi, n1 = A0y + oi, n2 = A0z + oi, n3 = A0w + oi;
        const float a1 = (n2 - n0) * (n3 - n1);
        const float ix1 = fmaxf(n0, q0), iy1 = fmaxf(n1, q1);
        const float ix2 = fminf(n2, q2), iy2 = fminf(n3, q3);
        const float inter = fmaxf(ix2 - ix1, 0.0f) * fmaxf(iy2 - iy1, 0.0f);
        const float iou = inter / ((a1 + a2) - inter);
        sup = (iou > 0.5f);
      }
      if (L1 == l0) {
        const float n0 = A1x + oi, n1 = A1y + oi, n2 = A1z + oi, n3 = A1w + oi;
        const float a1 = (n2 - n0) * (n3 - n1);
        const float ix1 = fmaxf(n0, q0), iy1 = fmaxf(n1, q1);
        const float ix2 = fminf(n2, q2), iy2 = fminf(n3, q3);
        const float inter = fmaxf(ix2 - ix1, 0.0f) * fmaxf(iy2 - iy1, 0.0f);
        const float iou = inter / ((a1 + a2) - inter);
        sup = sup || (iou > 0.5f);
      }
      if (!__any(sup ? 1 : 0)) {
        if (nacc < 64) {
          if (lane == nacc) { A0x = b0.x; A0y = b0.y; A0z = b0.z; A0w = b0.w; L0 = l0; }
        } else {
          if (lane == nacc - 64) { A1x = b0.x; A1y = b0.y; A1z = b0.z; A1w = b0.w; L1 = l0; }
        }
        if (lane == 0) { selbox[nacc] = b0; selkey[nacc] = k0; sellbl[nacc] = l0; }
        ++nacc;
        if (nacc == 100) break;
      }
      k0 = k1; b0 = b1; l0 = l1;
      k1 = k2; b1 = b2; l1 = l2;
    }
    if (lane == 0) snacc = nacc;
  }
  __syncthreads();

  if (snacc < 100 && nR > 0) {
    const float4* gR = reinterpret_cast<const float4*>(ws_f + RBOX_OFF) + (size_t)b * CAP;
    const unsigned long long* gRk =
        reinterpret_cast<const unsigned long long*>(ws_i + RKEY_OFF) + (size_t)b * CAP;
    for (int j = t; j < CAP; j += 256) {
      const unsigned long long k = (j < nR) ? gRk[j] : 0ull;
      rkeyS2[j] = k;
      if (j < nR) {
        rboxS2[j] = gR[j];
        const unsigned oid = 0xFFFFFFFFu - (unsigned)(k & 0xFFFFFFFFull);
        rlblS2[j] = (int)(oid % 90u) + 1;
      }
    }
    __syncthreads();
    if (t < 64) {
      while (nacc < 100) {
        unsigned long long mk = 0ull; int mi = 0;
        for (int j = lane; j < nR; j += 64) {
          const unsigned long long k = rkeyS2[j];
          if (k > mk) { mk = k; mi = j; }
        }
        for (int mm = 1; mm < 64; mm <<= 1) {
          const unsigned long long ok = __shfl_xor(mk, mm);
          const int om = __shfl_xor(mi, mm);
          if (ok > mk) { mk = ok; mi = om; }
        }
        if (mk == 0ull) break;
        if (lane == 0) rkeyS2[mi] = 0ull;
        __asm__ volatile("s_waitcnt lgkmcnt(0)" ::: "memory");
        const int lbl = rlblS2[mi];
        const float4 bb = rboxS2[mi];
        const float oi = (float)lbl * maxp1;
        const float q0 = bb.x + oi, q1 = bb.y + oi;
        const float q2 = bb.z + oi, q3 = bb.w + oi;
        const float a2 = (q2 - q0) * (q3 - q1);
        bool sup = false;
        if (L0 == lbl) {
          const float n0 = A0x + oi, n1 = A0y + oi, n2 = A0z + oi, n3 = A0w + oi;
          const float a1 = (n2 - n0) * (n3 - n1);
          const float ix1 = fmaxf(n0, q0), iy1 = fmaxf(n1, q1);
          const float ix2 = fminf(n2, q2), iy2 = fminf(n3, q3);
          const float inter = fmaxf(ix2 - ix1, 0.0f) * fmaxf(iy2 - iy1, 0.0f);
          const float iou = inter / ((a1 + a2) - inter);
          sup = (iou > 0.5f);
        }
        if (L1 == lbl) {
          const float n0 = A1x + oi, n1 = A1y + oi, n2 = A1z + oi, n3 = A1w + oi;
          const float a1 = (n2 - n0) * (n3 - n1);
          const float ix1 = fmaxf(n0, q0), iy1 = fmaxf(n1, q1);
          const float ix2 = fminf(n2, q2), iy2 = fminf(n3, q3);
          const float inter = fmaxf(ix2 - ix1, 0.0f) * fmaxf(iy2 - iy1, 0.0f);
          const float iou = inter / ((a1 + a2) - inter);
          sup = sup || (iou > 0.5f);
        }
        if (!__any(sup ? 1 : 0)) {
          if (nacc < 64) {
            if (lane == nacc) { A0x = bb.x; A0y = bb.y; A0z = bb.z; A0w = bb.w; L0 = lbl; }
          } else {
            if (lane == nacc - 64) { A1x = bb.x; A1y = bb.y; A1z = bb.z; A1w = bb.w; L1 = lbl; }
          }
          if (lane == 0) { selbox[nacc] = bb; selkey[nacc] = mk; sellbl[nacc] = lbl; }
          ++nacc;
        }
      }
      if (lane == 0) snacc = nacc;
    }
    __syncthreads();
  }

  const int nf = snacc;
  for (int k2 = t; k2 < 100; k2 += 256) {
    float o0 = 0.f, o1 = 0.f, o2 = 0.f, o3 = 0.f, sc = 0.f, lb = 0.f;
    if (k2 < nf) {
      const float4 v = selbox[k2];
      o0 = v.x; o1 = v.y; o2 = v.z; o3 = v.w;
      sc = __uint_as_float((unsigned)(selkey[k2] >> 32) & 0x7FFFFFFFu);
      lb = (float)sellbl[k2];
    }
    float* ob = out + ((size_t)b * 100 + k2) * 4;
    ob[0] = o0; ob[1] = o1; ob[2] = o2; ob[3] = o3;
    out[NB * 100 * 4 + b * 100 + k2] = sc;
    out[NB * 100 * 4 + NB * 100 + b * 100 + k2] = lb;
  }
}

extern "C" void kernel_launch(void* const* d_in, const int* in_sizes, int n_in,
                              void* d_out, int out_size, void* d_ws, size_t ws_size,
                              hipStream_t stream) {
  const float* logits = (const float*)d_in[0];
  const float* rel = (const float*)d_in[1];
  const float* props = (const float*)d_in[2];
  float* out = (float*)d_out;
  int* ws_i = (int*)d_ws;
  float* ws_f = (float*)d_ws;

  hipMemsetAsync(d_ws, 0, (size_t)ZERO_WORDS * 4, stream);
  cand_kernel<<<NB * BPI, 256, 0, stream>>>(logits, rel, props, ws_i, ws_f);
  hist_kernel<<<NB * GWB, 256, 0, stream>>>(ws_i, ws_f);
  gather_kernel<<<NB * GWB, 256, 0, stream>>>(ws_i, ws_f);
  matrix_kernel<<<NB * MWB, 256, 0, stream>>>(ws_i, ws_f, ws_i, ws_f);
  greedy_kernel<<<NB, 256, 0, stream>>>(ws_i, ws_f, out);
}